// Round 1
// baseline (1247.538 us; speedup 1.0000x reference)
//
#include <hip/hip_runtime.h>
#include <math.h>

__device__ __forceinline__ float leaky02(float v) { return v > 0.f ? v : 0.2f * v; }
__device__ __forceinline__ float eluf(float v) { return v > 0.f ? v : __expf(v) - 1.f; }

// ---------------- zero counts ----------------
__global__ __launch_bounds__(256) void k_zero(int* __restrict__ p, int n) {
    int t = blockIdx.x * 256 + threadIdx.x;
    if (t < n) p[t] = 0;
}

// ---------------- GEMM1: h1 = x @ w1 (+ as1/ad1) ----------------
// grid = 2*nb blocks; even/odd blockIdx picks output-channel half (64 ch)
__global__ __launch_bounds__(256) void k_gemm1(
    const float* __restrict__ x, const float* __restrict__ w1,
    const float* __restrict__ a1s, const float* __restrict__ a1d,
    float* __restrict__ h1, float* __restrict__ as1, float* __restrict__ ad1, int N)
{
    __shared__ float wT[64][132];   // [c_local][k], pad 4 -> row stride 528B (16B-mult, 8-way min conflict)
    const int half = blockIdx.x & 1;
    const int bid  = blockIdx.x >> 1;
    const int nb   = gridDim.x >> 1;
    const int tid  = threadIdx.x;
    const int wv   = tid >> 6, lane = tid & 63;

    for (int i = tid; i < 64 * 128; i += 256) {
        int c = i >> 7, k = i & 127;
        wT[c][k] = w1[k * 128 + half * 64 + c];
    }
    __syncthreads();

    const int c   = half * 64 + lane;
    const float a_s = a1s[c], a_d = a1d[c];
    const int hh  = c >> 5;

    for (int r = bid * 4 + wv; r < N; r += nb * 4) {
        const float* xrow = x + (size_t)r * 128;
        float2 xv = *(const float2*)(xrow + lane * 2);   // lane holds x[2l], x[2l+1]
        float acc = 0.f;
#pragma unroll
        for (int k4 = 0; k4 < 32; ++k4) {
            float p0x = __shfl(xv.x, 2 * k4);
            float p0y = __shfl(xv.y, 2 * k4);
            float p1x = __shfl(xv.x, 2 * k4 + 1);
            float p1y = __shfl(xv.y, 2 * k4 + 1);
            float4 wv4 = *(const float4*)&wT[lane][k4 * 4];
            acc = fmaf(p0x, wv4.x, acc);
            acc = fmaf(p0y, wv4.y, acc);
            acc = fmaf(p1x, wv4.z, acc);
            acc = fmaf(p1y, wv4.w, acc);
        }
        h1[(size_t)r * 128 + c] = acc;
        float ps_ = acc * a_s, pd_ = acc * a_d;
#pragma unroll
        for (int s = 1; s < 32; s <<= 1) {
            ps_ += __shfl_xor(ps_, s);
            pd_ += __shfl_xor(pd_, s);
        }
        if ((lane & 31) == 0) {
            as1[(size_t)r * 4 + hh] = ps_;
            ad1[(size_t)r * 4 + hh] = pd_;
        }
    }
}

// ---------------- CSR build ----------------
__global__ __launch_bounds__(256) void k_hist(const int* __restrict__ ei, int* __restrict__ counts,
                                              int E, int Et) {
    int t = blockIdx.x * 256 + threadIdx.x;
    if (t >= Et) return;
    int dd = (t < E) ? ei[E + t] : (t - E);
    atomicAdd(&counts[dd], 1);
}

__global__ __launch_bounds__(1024) void k_scan(const int* __restrict__ counts,
                                               int* __restrict__ rowp, int* __restrict__ pos, int N) {
    __shared__ int ps[1024];
    int t = threadIdx.x;
    int chunk = (N + 1023) >> 10;
    int b0 = t * chunk;
    int b1 = b0 + chunk; if (b1 > N) b1 = N;
    int s = 0;
    for (int i = b0; i < b1; ++i) s += counts[i];
    ps[t] = s;
    __syncthreads();
    for (int off = 1; off < 1024; off <<= 1) {
        int v = (t >= off) ? ps[t - off] : 0;
        __syncthreads();
        ps[t] += v;
        __syncthreads();
    }
    int run = ps[t] - s;   // exclusive prefix
    for (int i = b0; i < b1; ++i) {
        int cv = counts[i];
        rowp[i] = run; pos[i] = run;
        run += cv;
    }
    if (t == 1023) rowp[N] = ps[1023];
}

__global__ __launch_bounds__(256) void k_fill(const int* __restrict__ ei, int* __restrict__ pos,
                                              int* __restrict__ col, int E, int Et) {
    int t = blockIdx.x * 256 + threadIdx.x;
    if (t >= Et) return;
    int s, dd;
    if (t < E) { s = ei[t]; dd = ei[E + t]; } else { s = dd = t - E; }
    int p = atomicAdd(&pos[dd], 1);
    col[p] = s;
}

// ---------------- layer-1 aggregation (wave per dst node) ----------------
__global__ __launch_bounds__(256) void k_agg1(
    const int* __restrict__ rowp, const int* __restrict__ col,
    const float* __restrict__ as1, const float* __restrict__ ad1,
    const float* __restrict__ h1, const float* __restrict__ b1,
    float* __restrict__ out1, int N)
{
    const int lane = threadIdx.x & 63;
    const int wid  = (blockIdx.x * 256 + threadIdx.x) >> 6;
    const int nw   = (gridDim.x * 256) >> 6;
    for (int n = wid; n < N; n += nw) {
        const int start = rowp[n], end = rowp[n + 1];
        const float4 ad4 = *(const float4*)(ad1 + (size_t)n * 4);
        float m0 = -1e30f, m1 = -1e30f, m2 = -1e30f, m3 = -1e30f;
        float d0 = 0.f, d1 = 0.f, d2 = 0.f, d3 = 0.f;
        for (int j = start + lane; j < end; j += 64) {
            int s = col[j];
            float4 a4 = *(const float4*)(as1 + (size_t)s * 4);
            float e, nm;
            e = leaky02(a4.x + ad4.x); nm = fmaxf(m0, e); d0 = d0 * __expf(m0 - nm) + __expf(e - nm); m0 = nm;
            e = leaky02(a4.y + ad4.y); nm = fmaxf(m1, e); d1 = d1 * __expf(m1 - nm) + __expf(e - nm); m1 = nm;
            e = leaky02(a4.z + ad4.z); nm = fmaxf(m2, e); d2 = d2 * __expf(m2 - nm) + __expf(e - nm); m2 = nm;
            e = leaky02(a4.w + ad4.w); nm = fmaxf(m3, e); d3 = d3 * __expf(m3 - nm) + __expf(e - nm); m3 = nm;
        }
#pragma unroll
        for (int sft = 1; sft < 64; sft <<= 1) {
            float om, od, nm;
            om = __shfl_xor(m0, sft); od = __shfl_xor(d0, sft);
            nm = fmaxf(m0, om); d0 = d0 * __expf(m0 - nm) + od * __expf(om - nm); m0 = nm;
            om = __shfl_xor(m1, sft); od = __shfl_xor(d1, sft);
            nm = fmaxf(m1, om); d1 = d1 * __expf(m1 - nm) + od * __expf(om - nm); m1 = nm;
            om = __shfl_xor(m2, sft); od = __shfl_xor(d2, sft);
            nm = fmaxf(m2, om); d2 = d2 * __expf(m2 - nm) + od * __expf(om - nm); m2 = nm;
            om = __shfl_xor(m3, sft); od = __shfl_xor(d3, sft);
            nm = fmaxf(m3, om); d3 = d3 * __expf(m3 - nm) + od * __expf(om - nm); m3 = nm;
        }
        // lane owns channels 2*lane, 2*lane+1 -> head = lane>>4 (both channels same head)
        const int h = lane >> 4;
        const float mh  = (h == 0) ? m0 : (h == 1) ? m1 : (h == 2) ? m2 : m3;
        const float dh  = (h == 0) ? d0 : (h == 1) ? d1 : (h == 2) ? d2 : d3;
        const float adh = (h == 0) ? ad4.x : (h == 1) ? ad4.y : (h == 2) ? ad4.z : ad4.w;
        const float rdh = 1.f / (dh + 1e-16f);
        float acc0 = 0.f, acc1 = 0.f;
        for (int j = start; j < end; ++j) {
            int s = col[j];                       // uniform across wave
            float asv = as1[(size_t)s * 4 + h];
            float alpha = __expf(leaky02(asv + adh) - mh) * rdh;
            float2 hv = *(const float2*)(h1 + (size_t)s * 128 + lane * 2);
            acc0 = fmaf(alpha, hv.x, acc0);
            acc1 = fmaf(alpha, hv.y, acc1);
        }
        float2 bv = *(const float2*)(b1 + lane * 2);
        float2 o;
        o.x = eluf(acc0 + bv.x);
        o.y = eluf(acc1 + bv.y);
        *(float2*)(out1 + (size_t)n * 128 + lane * 2) = o;
    }
}

// ---------------- GEMM2: z2 = out1 @ w2 (+ as2/ad2) ----------------
__global__ __launch_bounds__(256) void k_gemm2(
    const float* __restrict__ out1, const float* __restrict__ w2,
    const float* __restrict__ a2s, const float* __restrict__ a2d,
    float* __restrict__ z2, float* __restrict__ as2, float* __restrict__ ad2, int N)
{
    __shared__ float w2T[32][132];
    const int tid = threadIdx.x;
    for (int i = tid; i < 32 * 128; i += 256) {
        int c = i >> 7, k = i & 127;
        w2T[c][k] = w2[k * 32 + c];
    }
    __syncthreads();
    const int wv = tid >> 6, lane = tid & 63;
    const int part = lane >> 5, cl = lane & 31;
    const int wid = blockIdx.x * 4 + wv, nw = gridDim.x * 4;
    const float acs = a2s[cl], acd = a2d[cl];
    for (int rp = wid; rp * 2 < N; rp += nw) {
        int r = rp * 2 + part;
        int rload = (r < N) ? r : (N - 1);
        float4 xv = *(const float4*)(out1 + (size_t)rload * 128 + cl * 4);  // half-wave holds the row
        float acc = 0.f;
#pragma unroll
        for (int k4 = 0; k4 < 32; ++k4) {
            int sl = part * 32 + k4;
            float px = __shfl(xv.x, sl);
            float py = __shfl(xv.y, sl);
            float pz = __shfl(xv.z, sl);
            float pw = __shfl(xv.w, sl);
            float4 wv4 = *(const float4*)&w2T[cl][k4 * 4];
            acc = fmaf(px, wv4.x, acc);
            acc = fmaf(py, wv4.y, acc);
            acc = fmaf(pz, wv4.z, acc);
            acc = fmaf(pw, wv4.w, acc);
        }
        if (r < N) {
            z2[(size_t)r * 32 + cl] = acc;
            float ps_ = acc * acs, pd_ = acc * acd;
#pragma unroll
            for (int s = 1; s < 32; s <<= 1) {
                ps_ += __shfl_xor(ps_, s);
                pd_ += __shfl_xor(pd_, s);
            }
            if (cl == 0) { as2[r] = ps_; ad2[r] = pd_; }
        }
    }
}

// ---------------- layer-2 aggregation + final linear (wave per dst node) ----------------
__global__ __launch_bounds__(256) void k_agg2(
    const int* __restrict__ rowp, const int* __restrict__ col,
    const float* __restrict__ as2, const float* __restrict__ ad2,
    const float* __restrict__ z2, const float* __restrict__ b2,
    const float* __restrict__ wl, const float* __restrict__ bl,
    float* __restrict__ out, int N)
{
    const int lane = threadIdx.x & 63;
    const int wid  = (blockIdx.x * 256 + threadIdx.x) >> 6;
    const int nw   = (gridDim.x * 256) >> 6;
    const int part = lane >> 5, cl = lane & 31;
    for (int n = wid; n < N; n += nw) {
        const int start = rowp[n], end = rowp[n + 1];
        const float adn = ad2[n];
        float m = -1e30f, d = 0.f;
        for (int j = start + lane; j < end; j += 64) {
            int s = col[j];
            float e = leaky02(as2[s] + adn);
            float nm = fmaxf(m, e);
            d = d * __expf(m - nm) + __expf(e - nm);
            m = nm;
        }
#pragma unroll
        for (int sft = 1; sft < 64; sft <<= 1) {
            float om = __shfl_xor(m, sft), od = __shfl_xor(d, sft);
            float nm = fmaxf(m, om);
            d = d * __expf(m - nm) + od * __expf(om - nm);
            m = nm;
        }
        const float rd = 1.f / (d + 1e-16f);
        float acc = 0.f;
        for (int j = start + part; j < end; j += 2) {   // two edges per wave-iter
            int s = col[j];
            float alpha = __expf(leaky02(as2[s] + adn) - m) * rd;
            acc = fmaf(alpha, z2[(size_t)s * 32 + cl], acc);
        }
        acc += __shfl_xor(acc, 32);
        float h2v = eluf(acc + b2[cl]);
        float p = h2v * wl[cl];
#pragma unroll
        for (int sft = 1; sft < 32; sft <<= 1) p += __shfl_xor(p, sft);
        if (lane == 0) out[n] = p + bl[0];
    }
}

extern "C" void kernel_launch(void* const* d_in, const int* in_sizes, int n_in,
                              void* d_out, int out_size, void* d_ws, size_t ws_size,
                              hipStream_t stream) {
    const float* x   = (const float*)d_in[0];
    const int*   ei  = (const int*)d_in[1];
    const float* w1  = (const float*)d_in[2];
    const float* a1s = (const float*)d_in[3];
    const float* a1d = (const float*)d_in[4];
    const float* b1  = (const float*)d_in[5];
    const float* w2  = (const float*)d_in[6];
    const float* a2s = (const float*)d_in[7];
    const float* a2d = (const float*)d_in[8];
    const float* b2  = (const float*)d_in[9];
    const float* wl  = (const float*)d_in[10];
    const float* bl  = (const float*)d_in[11];
    float* out = (float*)d_out;

    const int N  = in_sizes[0] / 128;
    const int E  = in_sizes[1] / 2;
    const int Et = E + N;

    float* ws   = (float*)d_ws;
    float* h1   = ws;                       // N*128
    float* out1 = h1   + (size_t)N * 128;   // N*128
    float* as1  = out1 + (size_t)N * 128;   // N*4
    float* ad1  = as1  + (size_t)N * 4;     // N*4
    float* z2   = ad1  + (size_t)N * 4;     // N*32
    float* as2  = z2   + (size_t)N * 32;    // N
    float* ad2  = as2  + N;                 // N
    int* counts = (int*)(ad2 + N);          // N
    int* rowp   = counts + N;               // N+1
    int* col    = rowp + (N + 1);           // Et
    int* pos    = col + Et;                 // N

    k_zero<<<(N + 255) / 256, 256, 0, stream>>>(counts, N);
    k_gemm1<<<2048, 256, 0, stream>>>(x, w1, a1s, a1d, h1, as1, ad1, N);
    k_hist<<<(Et + 255) / 256, 256, 0, stream>>>(ei, counts, E, Et);
    k_scan<<<1, 1024, 0, stream>>>(counts, rowp, pos, N);
    k_fill<<<(Et + 255) / 256, 256, 0, stream>>>(ei, pos, col, E, Et);
    k_agg1<<<4096, 256, 0, stream>>>(rowp, col, as1, ad1, h1, b1, out1, N);
    k_gemm2<<<2048, 256, 0, stream>>>(out1, w2, a2s, a2d, z2, as2, ad2, N);
    k_agg2<<<4096, 256, 0, stream>>>(rowp, col, as2, ad2, z2, b2, wl, bl, out, N);
}

// Round 2
// 862.772 us; speedup vs baseline: 1.4460x; 1.4460x over previous
//
#include <hip/hip_runtime.h>
#include <math.h>

__device__ __forceinline__ float leaky02(float v) { return v > 0.f ? v : 0.2f * v; }
__device__ __forceinline__ float eluf(float v) { return v > 0.f ? v : __expf(v) - 1.f; }

// ---------------- zero counts ----------------
__global__ __launch_bounds__(256) void k_zero(int* __restrict__ p, int n) {
    int t = blockIdx.x * 256 + threadIdx.x;
    if (t < n) p[t] = 0;
}

// ---------------- GEMM1: h1 = x @ w1 (+ as1/ad1) ----------------
// grid = 2 * ceil(N/64); even/odd blockIdx picks output-channel half (64 ch).
// LDS: x tile [64 rows][128 k] XOR-swizzled (k4 ^= r&7) + W half [128 k][64 c].
// Thread: 4 rows x 4 channels. Per k: 4x b32 (<=2-way bank) + 1x b128 (free) + 16 FMA.
__global__ __launch_bounds__(256, 2) void k_gemm1(
    const float* __restrict__ x, const float* __restrict__ w1,
    const float* __restrict__ a1s, const float* __restrict__ a1d,
    float* __restrict__ h1, float* __restrict__ as1, float* __restrict__ ad1, int N)
{
    __shared__ float xs[64 * 128];   // 32 KB, swizzled
    __shared__ float wsh[128 * 64];  // 32 KB
    const int half = blockIdx.x & 1;
    const int tile = blockIdx.x >> 1;
    const int tid  = threadIdx.x;
    const int r_base = tile * 64;

    // stage W half: 8192 floats = 2048 float4
    for (int i = tid; i < 2048; i += 256) {
        int k = i >> 4, c4 = i & 15;
        float4 v = *(const float4*)(w1 + k * 128 + half * 64 + c4 * 4);
        *(float4*)(wsh + k * 64 + c4 * 4) = v;
    }
    // stage x tile (swizzled): 8192 floats = 2048 float4
    for (int i = tid; i < 2048; i += 256) {
        int r = i >> 5, k4 = i & 31;
        int rr = r_base + r; if (rr >= N) rr = N - 1;
        float4 v = *(const float4*)(x + (size_t)rr * 128 + k4 * 4);
        *(float4*)(xs + r * 128 + (k4 ^ (r & 7)) * 4) = v;
    }
    __syncthreads();

    const int c0 = (tid & 15) * 4;       // 16 groups x 4 ch = 64
    const int r0 = (tid >> 4) * 4;       // 16 groups x 4 rows = 64
    const int swz0 = ((r0 + 0) & 7) << 2;
    const int swz1 = ((r0 + 1) & 7) << 2;
    const int swz2 = ((r0 + 2) & 7) << 2;
    const int swz3 = ((r0 + 3) & 7) << 2;
    const float* xb0 = xs + (r0 + 0) * 128;
    const float* xb1 = xs + (r0 + 1) * 128;
    const float* xb2 = xs + (r0 + 2) * 128;
    const float* xb3 = xs + (r0 + 3) * 128;

    float4 acc0 = {0,0,0,0}, acc1 = {0,0,0,0}, acc2 = {0,0,0,0}, acc3 = {0,0,0,0};
#pragma unroll 4
    for (int k = 0; k < 128; ++k) {
        float4 wv = *(const float4*)(wsh + k * 64 + c0);
        float x0 = xb0[k ^ swz0];
        float x1 = xb1[k ^ swz1];
        float x2 = xb2[k ^ swz2];
        float x3 = xb3[k ^ swz3];
        acc0.x = fmaf(x0, wv.x, acc0.x); acc0.y = fmaf(x0, wv.y, acc0.y);
        acc0.z = fmaf(x0, wv.z, acc0.z); acc0.w = fmaf(x0, wv.w, acc0.w);
        acc1.x = fmaf(x1, wv.x, acc1.x); acc1.y = fmaf(x1, wv.y, acc1.y);
        acc1.z = fmaf(x1, wv.z, acc1.z); acc1.w = fmaf(x1, wv.w, acc1.w);
        acc2.x = fmaf(x2, wv.x, acc2.x); acc2.y = fmaf(x2, wv.y, acc2.y);
        acc2.z = fmaf(x2, wv.z, acc2.z); acc2.w = fmaf(x2, wv.w, acc2.w);
        acc3.x = fmaf(x3, wv.x, acc3.x); acc3.y = fmaf(x3, wv.y, acc3.y);
        acc3.z = fmaf(x3, wv.z, acc3.z); acc3.w = fmaf(x3, wv.w, acc3.w);
    }

    // epilogue: store h1, and reduce a-dot partials across the 8 lanes sharing a head
    const int cg = half * 64 + c0;                 // global channel base
    const float4 avs = *(const float4*)(a1s + cg);
    const float4 avd = *(const float4*)(a1d + cg);
    const int head = half * 2 + ((tid & 15) >> 3); // global head of this thread's 4 ch
    float4 accs[4] = {acc0, acc1, acc2, acc3};
#pragma unroll
    for (int i = 0; i < 4; ++i) {
        int r = r_base + r0 + i;
        float4 a = accs[i];
        float ps = a.x * avs.x + a.y * avs.y + a.z * avs.z + a.w * avs.w;
        float pd = a.x * avd.x + a.y * avd.y + a.z * avd.z + a.w * avd.w;
        ps += __shfl_xor(ps, 1); pd += __shfl_xor(pd, 1);
        ps += __shfl_xor(ps, 2); pd += __shfl_xor(pd, 2);
        ps += __shfl_xor(ps, 4); pd += __shfl_xor(pd, 4);
        if (r < N) {
            *(float4*)(h1 + (size_t)r * 128 + cg) = a;
            if ((tid & 7) == 0) {
                as1[(size_t)r * 4 + head] = ps;
                ad1[(size_t)r * 4 + head] = pd;
            }
        }
    }
}

// ---------------- CSR build ----------------
__global__ __launch_bounds__(256) void k_hist(const int* __restrict__ ei, int* __restrict__ counts,
                                              int E, int Et) {
    int t = blockIdx.x * 256 + threadIdx.x;
    if (t >= Et) return;
    int dd = (t < E) ? ei[E + t] : (t - E);
    atomicAdd(&counts[dd], 1);
}

__global__ __launch_bounds__(1024) void k_scan(const int* __restrict__ counts,
                                               int* __restrict__ rowp, int* __restrict__ pos, int N) {
    __shared__ int ps[1024];
    int t = threadIdx.x;
    int chunk = (N + 1023) >> 10;
    int b0 = t * chunk;
    int b1 = b0 + chunk; if (b1 > N) b1 = N;
    int s = 0;
    for (int i = b0; i < b1; ++i) s += counts[i];
    ps[t] = s;
    __syncthreads();
    for (int off = 1; off < 1024; off <<= 1) {
        int v = (t >= off) ? ps[t - off] : 0;
        __syncthreads();
        ps[t] += v;
        __syncthreads();
    }
    int run = ps[t] - s;   // exclusive prefix
    for (int i = b0; i < b1; ++i) {
        int cv = counts[i];
        rowp[i] = run; pos[i] = run;
        run += cv;
    }
    if (t == 1023) rowp[N] = ps[1023];
}

__global__ __launch_bounds__(256) void k_fill(const int* __restrict__ ei, int* __restrict__ pos,
                                              int* __restrict__ col, int E, int Et) {
    int t = blockIdx.x * 256 + threadIdx.x;
    if (t >= Et) return;
    int s, dd;
    if (t < E) { s = ei[t]; dd = ei[E + t]; } else { s = dd = t - E; }
    int p = atomicAdd(&pos[dd], 1);
    col[p] = s;
}

// ---------------- layer-1 aggregation (wave per dst node) ----------------
__global__ __launch_bounds__(256) void k_agg1(
    const int* __restrict__ rowp, const int* __restrict__ col,
    const float* __restrict__ as1, const float* __restrict__ ad1,
    const float* __restrict__ h1, const float* __restrict__ b1,
    float* __restrict__ out1, int N)
{
    const int lane = threadIdx.x & 63;
    const int wid  = (blockIdx.x * 256 + threadIdx.x) >> 6;
    const int nw   = (gridDim.x * 256) >> 6;
    const int part = lane >> 5;        // half-wave: which edge of the pair
    const int cl   = lane & 31;        // channel group: cl*4 .. cl*4+3
    const int hch  = cl >> 3;          // head of this channel group
    for (int n = wid; n < N; n += nw) {
        const int start = rowp[n], end = rowp[n + 1];
        const float4 ad4 = *(const float4*)(ad1 + (size_t)n * 4);
        // pass A: online softmax (m,d) per head, lane-parallel over edges
        float m0 = -1e30f, m1 = -1e30f, m2 = -1e30f, m3 = -1e30f;
        float d0 = 0.f, d1 = 0.f, d2 = 0.f, d3 = 0.f;
        for (int j = start + lane; j < end; j += 64) {
            int s = col[j];
            float4 a4 = *(const float4*)(as1 + (size_t)s * 4);
            float e, nm;
            e = leaky02(a4.x + ad4.x); nm = fmaxf(m0, e); d0 = d0 * __expf(m0 - nm) + __expf(e - nm); m0 = nm;
            e = leaky02(a4.y + ad4.y); nm = fmaxf(m1, e); d1 = d1 * __expf(m1 - nm) + __expf(e - nm); m1 = nm;
            e = leaky02(a4.z + ad4.z); nm = fmaxf(m2, e); d2 = d2 * __expf(m2 - nm) + __expf(e - nm); m2 = nm;
            e = leaky02(a4.w + ad4.w); nm = fmaxf(m3, e); d3 = d3 * __expf(m3 - nm) + __expf(e - nm); m3 = nm;
        }
#pragma unroll
        for (int sft = 1; sft < 64; sft <<= 1) {
            float om, od, nm;
            om = __shfl_xor(m0, sft); od = __shfl_xor(d0, sft);
            nm = fmaxf(m0, om); d0 = d0 * __expf(m0 - nm) + od * __expf(om - nm); m0 = nm;
            om = __shfl_xor(m1, sft); od = __shfl_xor(d1, sft);
            nm = fmaxf(m1, om); d1 = d1 * __expf(m1 - nm) + od * __expf(om - nm); m1 = nm;
            om = __shfl_xor(m2, sft); od = __shfl_xor(d2, sft);
            nm = fmaxf(m2, om); d2 = d2 * __expf(m2 - nm) + od * __expf(om - nm); m2 = nm;
            om = __shfl_xor(m3, sft); od = __shfl_xor(d3, sft);
            nm = fmaxf(m3, om); d3 = d3 * __expf(m3 - nm) + od * __expf(om - nm); m3 = nm;
        }
        const float mh  = (hch == 0) ? m0 : (hch == 1) ? m1 : (hch == 2) ? m2 : m3;
        const float dh  = (hch == 0) ? d0 : (hch == 1) ? d1 : (hch == 2) ? d2 : d3;
        const float adh = (hch == 0) ? ad4.x : (hch == 1) ? ad4.y : (hch == 2) ? ad4.z : ad4.w;
        const float rdh = 1.f / (dh + 1e-16f);
        // pass B: 2 edges per iteration, half-wave each; lane owns 4 channels
        float4 acc = {0,0,0,0};
        for (int j = start + part; j < end; j += 2) {
            int s = col[j];
            float asv = as1[(size_t)s * 4 + hch];
            float alpha = __expf(leaky02(asv + adh) - mh) * rdh;
            float4 hv = *(const float4*)(h1 + (size_t)s * 128 + cl * 4);
            acc.x = fmaf(alpha, hv.x, acc.x);
            acc.y = fmaf(alpha, hv.y, acc.y);
            acc.z = fmaf(alpha, hv.z, acc.z);
            acc.w = fmaf(alpha, hv.w, acc.w);
        }
        acc.x += __shfl_xor(acc.x, 32);
        acc.y += __shfl_xor(acc.y, 32);
        acc.z += __shfl_xor(acc.z, 32);
        acc.w += __shfl_xor(acc.w, 32);
        if (part == 0) {
            float4 bv = *(const float4*)(b1 + cl * 4);
            float4 o;
            o.x = eluf(acc.x + bv.x);
            o.y = eluf(acc.y + bv.y);
            o.z = eluf(acc.z + bv.z);
            o.w = eluf(acc.w + bv.w);
            *(float4*)(out1 + (size_t)n * 128 + cl * 4) = o;
        }
    }
}

// ---------------- GEMM2: z2 = out1 @ w2 (+ as2/ad2) ----------------
// 128 rows x 32 ch per block. LDS: x tile 64KB swizzled + W2 16KB.
__global__ __launch_bounds__(256, 2) void k_gemm2(
    const float* __restrict__ out1, const float* __restrict__ w2,
    const float* __restrict__ a2s, const float* __restrict__ a2d,
    float* __restrict__ z2, float* __restrict__ as2, float* __restrict__ ad2, int N)
{
    __shared__ float xs[128 * 128];  // 64 KB, swizzled
    __shared__ float wsh[128 * 32];  // 16 KB
    const int tid = threadIdx.x;
    const int r_base = blockIdx.x * 128;

    for (int i = tid; i < 1024; i += 256) {       // W2: 4096 floats
        int k = i >> 3, c4 = i & 7;
        float4 v = *(const float4*)(w2 + k * 32 + c4 * 4);
        *(float4*)(wsh + k * 32 + c4 * 4) = v;
    }
    for (int i = tid; i < 4096; i += 256) {       // x: 16384 floats
        int r = i >> 5, k4 = i & 31;
        int rr = r_base + r; if (rr >= N) rr = N - 1;
        float4 v = *(const float4*)(out1 + (size_t)rr * 128 + k4 * 4);
        *(float4*)(xs + r * 128 + (k4 ^ (r & 7)) * 4) = v;
    }
    __syncthreads();

    const int c0 = (tid & 7) * 4;      // 8 groups x 4 ch = 32
    const int r0 = (tid >> 3) * 4;     // 32 groups x 4 rows = 128
    const int swz0 = ((r0 + 0) & 7) << 2;
    const int swz1 = ((r0 + 1) & 7) << 2;
    const int swz2 = ((r0 + 2) & 7) << 2;
    const int swz3 = ((r0 + 3) & 7) << 2;
    const float* xb0 = xs + (r0 + 0) * 128;
    const float* xb1 = xs + (r0 + 1) * 128;
    const float* xb2 = xs + (r0 + 2) * 128;
    const float* xb3 = xs + (r0 + 3) * 128;

    float4 acc0 = {0,0,0,0}, acc1 = {0,0,0,0}, acc2 = {0,0,0,0}, acc3 = {0,0,0,0};
#pragma unroll 4
    for (int k = 0; k < 128; ++k) {
        float4 wv = *(const float4*)(wsh + k * 32 + c0);
        float x0 = xb0[k ^ swz0];
        float x1 = xb1[k ^ swz1];
        float x2 = xb2[k ^ swz2];
        float x3 = xb3[k ^ swz3];
        acc0.x = fmaf(x0, wv.x, acc0.x); acc0.y = fmaf(x0, wv.y, acc0.y);
        acc0.z = fmaf(x0, wv.z, acc0.z); acc0.w = fmaf(x0, wv.w, acc0.w);
        acc1.x = fmaf(x1, wv.x, acc1.x); acc1.y = fmaf(x1, wv.y, acc1.y);
        acc1.z = fmaf(x1, wv.z, acc1.z); acc1.w = fmaf(x1, wv.w, acc1.w);
        acc2.x = fmaf(x2, wv.x, acc2.x); acc2.y = fmaf(x2, wv.y, acc2.y);
        acc2.z = fmaf(x2, wv.z, acc2.z); acc2.w = fmaf(x2, wv.w, acc2.w);
        acc3.x = fmaf(x3, wv.x, acc3.x); acc3.y = fmaf(x3, wv.y, acc3.y);
        acc3.z = fmaf(x3, wv.z, acc3.z); acc3.w = fmaf(x3, wv.w, acc3.w);
    }

    const float4 avs = *(const float4*)(a2s + c0);
    const float4 avd = *(const float4*)(a2d + c0);
    float4 accs[4] = {acc0, acc1, acc2, acc3};
#pragma unroll
    for (int i = 0; i < 4; ++i) {
        int r = r_base + r0 + i;
        float4 a = accs[i];
        float ps = a.x * avs.x + a.y * avs.y + a.z * avs.z + a.w * avs.w;
        float pd = a.x * avd.x + a.y * avd.y + a.z * avd.z + a.w * avd.w;
        ps += __shfl_xor(ps, 1); pd += __shfl_xor(pd, 1);
        ps += __shfl_xor(ps, 2); pd += __shfl_xor(pd, 2);
        ps += __shfl_xor(ps, 4); pd += __shfl_xor(pd, 4);
        if (r < N) {
            *(float4*)(z2 + (size_t)r * 32 + c0) = a;
            if ((tid & 7) == 0) { as2[r] = ps; ad2[r] = pd; }
        }
    }
}

// ---------------- layer-2 aggregation + final linear (wave per dst node) ----------------
__global__ __launch_bounds__(256) void k_agg2(
    const int* __restrict__ rowp, const int* __restrict__ col,
    const float* __restrict__ as2, const float* __restrict__ ad2,
    const float* __restrict__ z2, const float* __restrict__ b2,
    const float* __restrict__ wl, const float* __restrict__ bl,
    float* __restrict__ out, int N)
{
    const int lane = threadIdx.x & 63;
    const int wid  = (blockIdx.x * 256 + threadIdx.x) >> 6;
    const int nw   = (gridDim.x * 256) >> 6;
    const int q  = lane >> 4;      // 0..3: edge slot
    const int cl = lane & 15;      // channels cl*2, cl*2+1
    for (int n = wid; n < N; n += nw) {
        const int start = rowp[n], end = rowp[n + 1];
        const float adn = ad2[n];
        float m = -1e30f, d = 0.f;
        for (int j = start + lane; j < end; j += 64) {
            int s = col[j];
            float e = leaky02(as2[s] + adn);
            float nm = fmaxf(m, e);
            d = d * __expf(m - nm) + __expf(e - nm);
            m = nm;
        }
#pragma unroll
        for (int sft = 1; sft < 64; sft <<= 1) {
            float om = __shfl_xor(m, sft), od = __shfl_xor(d, sft);
            float nm = fmaxf(m, om);
            d = d * __expf(m - nm) + od * __expf(om - nm);
            m = nm;
        }
        const float rd = 1.f / (d + 1e-16f);
        float2 acc = {0.f, 0.f};
        for (int j = start + q; j < end; j += 4) {   // 4 edges per wave-iter
            int s = col[j];
            float alpha = __expf(leaky02(as2[s] + adn) - m) * rd;
            float2 zv = *(const float2*)(z2 + (size_t)s * 32 + cl * 2);
            acc.x = fmaf(alpha, zv.x, acc.x);
            acc.y = fmaf(alpha, zv.y, acc.y);
        }
        acc.x += __shfl_xor(acc.x, 16); acc.y += __shfl_xor(acc.y, 16);
        acc.x += __shfl_xor(acc.x, 32); acc.y += __shfl_xor(acc.y, 32);
        float h0 = eluf(acc.x + b2[cl * 2]);
        float h1v = eluf(acc.y + b2[cl * 2 + 1]);
        float p = h0 * wl[cl * 2] + h1v * wl[cl * 2 + 1];
#pragma unroll
        for (int sft = 1; sft < 16; sft <<= 1) p += __shfl_xor(p, sft);
        if (lane == 0) out[n] = p + bl[0];
    }
}

extern "C" void kernel_launch(void* const* d_in, const int* in_sizes, int n_in,
                              void* d_out, int out_size, void* d_ws, size_t ws_size,
                              hipStream_t stream) {
    const float* x   = (const float*)d_in[0];
    const int*   ei  = (const int*)d_in[1];
    const float* w1  = (const float*)d_in[2];
    const float* a1s = (const float*)d_in[3];
    const float* a1d = (const float*)d_in[4];
    const float* b1  = (const float*)d_in[5];
    const float* w2  = (const float*)d_in[6];
    const float* a2s = (const float*)d_in[7];
    const float* a2d = (const float*)d_in[8];
    const float* b2  = (const float*)d_in[9];
    const float* wl  = (const float*)d_in[10];
    const float* bl  = (const float*)d_in[11];
    float* out = (float*)d_out;

    const int N  = in_sizes[0] / 128;
    const int E  = in_sizes[1] / 2;
    const int Et = E + N;

    float* ws   = (float*)d_ws;
    float* h1   = ws;                       // N*128
    float* out1 = h1   + (size_t)N * 128;   // N*128
    float* as1  = out1 + (size_t)N * 128;   // N*4
    float* ad1  = as1  + (size_t)N * 4;     // N*4
    float* z2   = ad1  + (size_t)N * 4;     // N*32
    float* as2  = z2   + (size_t)N * 32;    // N
    float* ad2  = as2  + N;                 // N
    int* counts = (int*)(ad2 + N);          // N
    int* rowp   = counts + N;               // N+1
    int* col    = rowp + (N + 1);           // Et
    int* pos    = col + Et;                 // N

    k_zero<<<(N + 255) / 256, 256, 0, stream>>>(counts, N);
    k_gemm1<<<2 * ((N + 63) / 64), 256, 0, stream>>>(x, w1, a1s, a1d, h1, as1, ad1, N);
    k_hist<<<(Et + 255) / 256, 256, 0, stream>>>(ei, counts, E, Et);
    k_scan<<<1, 1024, 0, stream>>>(counts, rowp, pos, N);
    k_fill<<<(Et + 255) / 256, 256, 0, stream>>>(ei, pos, col, E, Et);
    k_agg1<<<4096, 256, 0, stream>>>(rowp, col, as1, ad1, h1, b1, out1, N);
    k_gemm2<<<(N + 127) / 128, 256, 0, stream>>>(out1, w2, a2s, a2d, z2, as2, ad2, N);
    k_agg2<<<4096, 256, 0, stream>>>(rowp, col, as2, ad2, z2, b2, wl, bl, out, N);
}

// Round 3
// 651.681 us; speedup vs baseline: 1.9143x; 1.3239x over previous
//
#include <hip/hip_runtime.h>
#include <math.h>

__device__ __forceinline__ float leaky02(float v) { return v > 0.f ? v : 0.2f * v; }
__device__ __forceinline__ float eluf(float v) { return v > 0.f ? v : __expf(v) - 1.f; }

// ---------------- zero counts ----------------
__global__ __launch_bounds__(256) void k_zero(int* __restrict__ p, int n) {
    int t = blockIdx.x * 256 + threadIdx.x;
    if (t < n) p[t] = 0;
}

// ---------------- GEMM1: h1 = x @ w1 (+ as1/ad1) ----------------
__global__ __launch_bounds__(256, 2) void k_gemm1(
    const float* __restrict__ x, const float* __restrict__ w1,
    const float* __restrict__ a1s, const float* __restrict__ a1d,
    float* __restrict__ h1, float* __restrict__ as1, float* __restrict__ ad1, int N)
{
    __shared__ float xs[64 * 128];   // 32 KB, swizzled
    __shared__ float wsh[128 * 64];  // 32 KB
    const int half = blockIdx.x & 1;
    const int tile = blockIdx.x >> 1;
    const int tid  = threadIdx.x;
    const int r_base = tile * 64;

    for (int i = tid; i < 2048; i += 256) {
        int k = i >> 4, c4 = i & 15;
        float4 v = *(const float4*)(w1 + k * 128 + half * 64 + c4 * 4);
        *(float4*)(wsh + k * 64 + c4 * 4) = v;
    }
    for (int i = tid; i < 2048; i += 256) {
        int r = i >> 5, k4 = i & 31;
        int rr = r_base + r; if (rr >= N) rr = N - 1;
        float4 v = *(const float4*)(x + (size_t)rr * 128 + k4 * 4);
        *(float4*)(xs + r * 128 + (k4 ^ (r & 7)) * 4) = v;
    }
    __syncthreads();

    const int c0 = (tid & 15) * 4;
    const int r0 = (tid >> 4) * 4;
    const int swz0 = ((r0 + 0) & 7) << 2;
    const int swz1 = ((r0 + 1) & 7) << 2;
    const int swz2 = ((r0 + 2) & 7) << 2;
    const int swz3 = ((r0 + 3) & 7) << 2;
    const float* xb0 = xs + (r0 + 0) * 128;
    const float* xb1 = xs + (r0 + 1) * 128;
    const float* xb2 = xs + (r0 + 2) * 128;
    const float* xb3 = xs + (r0 + 3) * 128;

    float4 acc0 = {0,0,0,0}, acc1 = {0,0,0,0}, acc2 = {0,0,0,0}, acc3 = {0,0,0,0};
#pragma unroll 4
    for (int k = 0; k < 128; ++k) {
        float4 wv = *(const float4*)(wsh + k * 64 + c0);
        float x0 = xb0[k ^ swz0];
        float x1 = xb1[k ^ swz1];
        float x2 = xb2[k ^ swz2];
        float x3 = xb3[k ^ swz3];
        acc0.x = fmaf(x0, wv.x, acc0.x); acc0.y = fmaf(x0, wv.y, acc0.y);
        acc0.z = fmaf(x0, wv.z, acc0.z); acc0.w = fmaf(x0, wv.w, acc0.w);
        acc1.x = fmaf(x1, wv.x, acc1.x); acc1.y = fmaf(x1, wv.y, acc1.y);
        acc1.z = fmaf(x1, wv.z, acc1.z); acc1.w = fmaf(x1, wv.w, acc1.w);
        acc2.x = fmaf(x2, wv.x, acc2.x); acc2.y = fmaf(x2, wv.y, acc2.y);
        acc2.z = fmaf(x2, wv.z, acc2.z); acc2.w = fmaf(x2, wv.w, acc2.w);
        acc3.x = fmaf(x3, wv.x, acc3.x); acc3.y = fmaf(x3, wv.y, acc3.y);
        acc3.z = fmaf(x3, wv.z, acc3.z); acc3.w = fmaf(x3, wv.w, acc3.w);
    }

    const int cg = half * 64 + c0;
    const float4 avs = *(const float4*)(a1s + cg);
    const float4 avd = *(const float4*)(a1d + cg);
    const int head = half * 2 + ((tid & 15) >> 3);
    float4 accs[4] = {acc0, acc1, acc2, acc3};
#pragma unroll
    for (int i = 0; i < 4; ++i) {
        int r = r_base + r0 + i;
        float4 a = accs[i];
        float ps = a.x * avs.x + a.y * avs.y + a.z * avs.z + a.w * avs.w;
        float pd = a.x * avd.x + a.y * avd.y + a.z * avd.z + a.w * avd.w;
        ps += __shfl_xor(ps, 1); pd += __shfl_xor(pd, 1);
        ps += __shfl_xor(ps, 2); pd += __shfl_xor(pd, 2);
        ps += __shfl_xor(ps, 4); pd += __shfl_xor(pd, 4);
        if (r < N) {
            *(float4*)(h1 + (size_t)r * 128 + cg) = a;
            if ((tid & 7) == 0) {
                as1[(size_t)r * 4 + head] = ps;
                ad1[(size_t)r * 4 + head] = pd;
            }
        }
    }
}

// ---------------- CSR build ----------------
__global__ __launch_bounds__(256) void k_hist(const int* __restrict__ ei, int* __restrict__ counts,
                                              int E, int Et) {
    int t = blockIdx.x * 256 + threadIdx.x;
    if (t >= Et) return;
    int dd = (t < E) ? ei[E + t] : (t - E);
    atomicAdd(&counts[dd], 1);
}

// 3-phase device-wide exclusive scan of counts -> rowp/pos (segment = 1024)
__global__ __launch_bounds__(256) void k_bsum(const int* __restrict__ counts,
                                              int* __restrict__ bsum, int N) {
    int t = threadIdx.x;
    int base = blockIdx.x * 1024 + t * 4;
    int s = 0;
    if (base + 3 < N) { int4 v = *(const int4*)(counts + base); s = v.x + v.y + v.z + v.w; }
    else { for (int j = 0; j < 4; ++j) if (base + j < N) s += counts[base + j]; }
#pragma unroll
    for (int off = 1; off < 64; off <<= 1) s += __shfl_xor(s, off);
    __shared__ int wt[4];
    if ((t & 63) == 0) wt[t >> 6] = s;
    __syncthreads();
    if (t == 0) bsum[blockIdx.x] = wt[0] + wt[1] + wt[2] + wt[3];
}

__global__ __launch_bounds__(1024) void k_scansums(const int* __restrict__ bsum,
                                                   int* __restrict__ boff,
                                                   int* __restrict__ rowp_last, int NB) {
    __shared__ int ps[1024];
    int t = threadIdx.x;
    int v = (t < NB) ? bsum[t] : 0;
    ps[t] = v;
    __syncthreads();
    for (int off = 1; off < 1024; off <<= 1) {
        int u = (t >= off) ? ps[t - off] : 0;
        __syncthreads();
        ps[t] += u;
        __syncthreads();
    }
    if (t < NB) boff[t] = ps[t] - v;          // exclusive block offset
    if (t == NB - 1) *rowp_last = ps[t];      // total edge count
}

__global__ __launch_bounds__(256) void k_scatter(const int* __restrict__ counts,
                                                 const int* __restrict__ boff,
                                                 int* __restrict__ rowp, int* __restrict__ pos, int N) {
    int t = threadIdx.x;
    int lane = t & 63, wv = t >> 6;
    int base = blockIdx.x * 1024 + t * 4;
    int c0 = 0, c1 = 0, c2 = 0, c3 = 0;
    if (base + 3 < N) { int4 v = *(const int4*)(counts + base); c0 = v.x; c1 = v.y; c2 = v.z; c3 = v.w; }
    else {
        if (base     < N) c0 = counts[base];
        if (base + 1 < N) c1 = counts[base + 1];
        if (base + 2 < N) c2 = counts[base + 2];
        if (base + 3 < N) c3 = counts[base + 3];
    }
    int ts = c0 + c1 + c2 + c3;
    int inc = ts;
#pragma unroll
    for (int off = 1; off < 64; off <<= 1) { int u = __shfl_up(inc, off); if (lane >= off) inc += u; }
    int excl = inc - ts;
    __shared__ int wt[4];
    if (lane == 63) wt[wv] = inc;
    __syncthreads();
    int woff = 0;
    for (int i = 0; i < wv; ++i) woff += wt[i];
    int p = boff[blockIdx.x] + woff + excl;
    if (base     < N) { rowp[base]     = p; pos[base]     = p; p += c0; }
    if (base + 1 < N) { rowp[base + 1] = p; pos[base + 1] = p; p += c1; }
    if (base + 2 < N) { rowp[base + 2] = p; pos[base + 2] = p; p += c2; }
    if (base + 3 < N) { rowp[base + 3] = p; pos[base + 3] = p; p += c3; }
}

__global__ __launch_bounds__(256) void k_fill(const int* __restrict__ ei, int* __restrict__ pos,
                                              int* __restrict__ col, int E, int Et) {
    int t = blockIdx.x * 256 + threadIdx.x;
    if (t >= Et) return;
    int s, dd;
    if (t < E) { s = ei[t]; dd = ei[E + t]; } else { s = dd = t - E; }
    int p = atomicAdd(&pos[dd], 1);
    col[p] = s;
}

// ---------------- layer-1 aggregation (wave per dst node) ----------------
__global__ __launch_bounds__(256) void k_agg1(
    const int* __restrict__ rowp, const int* __restrict__ col,
    const float* __restrict__ as1, const float* __restrict__ ad1,
    const float* __restrict__ h1, const float* __restrict__ b1,
    float* __restrict__ out1, int N)
{
    const int lane = threadIdx.x & 63;
    const int wid  = (blockIdx.x * 256 + threadIdx.x) >> 6;
    const int nw   = (gridDim.x * 256) >> 6;
    const int part = lane >> 5;
    const int cl   = lane & 31;
    const int hch  = cl >> 3;
    for (int n = wid; n < N; n += nw) {
        const int start = rowp[n], end = rowp[n + 1];
        const float4 ad4 = *(const float4*)(ad1 + (size_t)n * 4);
        float m0 = -1e30f, m1 = -1e30f, m2 = -1e30f, m3 = -1e30f;
        float d0 = 0.f, d1 = 0.f, d2 = 0.f, d3 = 0.f;
        for (int j = start + lane; j < end; j += 64) {
            int s = col[j];
            float4 a4 = *(const float4*)(as1 + (size_t)s * 4);
            float e, nm;
            e = leaky02(a4.x + ad4.x); nm = fmaxf(m0, e); d0 = d0 * __expf(m0 - nm) + __expf(e - nm); m0 = nm;
            e = leaky02(a4.y + ad4.y); nm = fmaxf(m1, e); d1 = d1 * __expf(m1 - nm) + __expf(e - nm); m1 = nm;
            e = leaky02(a4.z + ad4.z); nm = fmaxf(m2, e); d2 = d2 * __expf(m2 - nm) + __expf(e - nm); m2 = nm;
            e = leaky02(a4.w + ad4.w); nm = fmaxf(m3, e); d3 = d3 * __expf(m3 - nm) + __expf(e - nm); m3 = nm;
        }
#pragma unroll
        for (int sft = 1; sft < 64; sft <<= 1) {
            float om, od, nm;
            om = __shfl_xor(m0, sft); od = __shfl_xor(d0, sft);
            nm = fmaxf(m0, om); d0 = d0 * __expf(m0 - nm) + od * __expf(om - nm); m0 = nm;
            om = __shfl_xor(m1, sft); od = __shfl_xor(d1, sft);
            nm = fmaxf(m1, om); d1 = d1 * __expf(m1 - nm) + od * __expf(om - nm); m1 = nm;
            om = __shfl_xor(m2, sft); od = __shfl_xor(d2, sft);
            nm = fmaxf(m2, om); d2 = d2 * __expf(m2 - nm) + od * __expf(om - nm); m2 = nm;
            om = __shfl_xor(m3, sft); od = __shfl_xor(d3, sft);
            nm = fmaxf(m3, om); d3 = d3 * __expf(m3 - nm) + od * __expf(om - nm); m3 = nm;
        }
        const float mh  = (hch == 0) ? m0 : (hch == 1) ? m1 : (hch == 2) ? m2 : m3;
        const float dh  = (hch == 0) ? d0 : (hch == 1) ? d1 : (hch == 2) ? d2 : d3;
        const float adh = (hch == 0) ? ad4.x : (hch == 1) ? ad4.y : (hch == 2) ? ad4.z : ad4.w;
        const float rdh = 1.f / (dh + 1e-16f);
        float4 acc = {0,0,0,0};
        for (int j = start + part; j < end; j += 2) {
            int s = col[j];
            float asv = as1[(size_t)s * 4 + hch];
            float alpha = __expf(leaky02(asv + adh) - mh) * rdh;
            float4 hv = *(const float4*)(h1 + (size_t)s * 128 + cl * 4);
            acc.x = fmaf(alpha, hv.x, acc.x);
            acc.y = fmaf(alpha, hv.y, acc.y);
            acc.z = fmaf(alpha, hv.z, acc.z);
            acc.w = fmaf(alpha, hv.w, acc.w);
        }
        acc.x += __shfl_xor(acc.x, 32);
        acc.y += __shfl_xor(acc.y, 32);
        acc.z += __shfl_xor(acc.z, 32);
        acc.w += __shfl_xor(acc.w, 32);
        if (part == 0) {
            float4 bv = *(const float4*)(b1 + cl * 4);
            float4 o;
            o.x = eluf(acc.x + bv.x);
            o.y = eluf(acc.y + bv.y);
            o.z = eluf(acc.z + bv.z);
            o.w = eluf(acc.w + bv.w);
            *(float4*)(out1 + (size_t)n * 128 + cl * 4) = o;
        }
    }
}

// ---------------- GEMM2: z2 = out1 @ w2 (+ as2/ad2) ----------------
__global__ __launch_bounds__(256, 2) void k_gemm2(
    const float* __restrict__ out1, const float* __restrict__ w2,
    const float* __restrict__ a2s, const float* __restrict__ a2d,
    float* __restrict__ z2, float* __restrict__ as2, float* __restrict__ ad2, int N)
{
    __shared__ float xs[128 * 128];
    __shared__ float wsh[128 * 32];
    const int tid = threadIdx.x;
    const int r_base = blockIdx.x * 128;

    for (int i = tid; i < 1024; i += 256) {
        int k = i >> 3, c4 = i & 7;
        float4 v = *(const float4*)(w2 + k * 32 + c4 * 4);
        *(float4*)(wsh + k * 32 + c4 * 4) = v;
    }
    for (int i = tid; i < 4096; i += 256) {
        int r = i >> 5, k4 = i & 31;
        int rr = r_base + r; if (rr >= N) rr = N - 1;
        float4 v = *(const float4*)(out1 + (size_t)rr * 128 + k4 * 4);
        *(float4*)(xs + r * 128 + (k4 ^ (r & 7)) * 4) = v;
    }
    __syncthreads();

    const int c0 = (tid & 7) * 4;
    const int r0 = (tid >> 3) * 4;
    const int swz0 = ((r0 + 0) & 7) << 2;
    const int swz1 = ((r0 + 1) & 7) << 2;
    const int swz2 = ((r0 + 2) & 7) << 2;
    const int swz3 = ((r0 + 3) & 7) << 2;
    const float* xb0 = xs + (r0 + 0) * 128;
    const float* xb1 = xs + (r0 + 1) * 128;
    const float* xb2 = xs + (r0 + 2) * 128;
    const float* xb3 = xs + (r0 + 3) * 128;

    float4 acc0 = {0,0,0,0}, acc1 = {0,0,0,0}, acc2 = {0,0,0,0}, acc3 = {0,0,0,0};
#pragma unroll 4
    for (int k = 0; k < 128; ++k) {
        float4 wv = *(const float4*)(wsh + k * 32 + c0);
        float x0 = xb0[k ^ swz0];
        float x1 = xb1[k ^ swz1];
        float x2 = xb2[k ^ swz2];
        float x3 = xb3[k ^ swz3];
        acc0.x = fmaf(x0, wv.x, acc0.x); acc0.y = fmaf(x0, wv.y, acc0.y);
        acc0.z = fmaf(x0, wv.z, acc0.z); acc0.w = fmaf(x0, wv.w, acc0.w);
        acc1.x = fmaf(x1, wv.x, acc1.x); acc1.y = fmaf(x1, wv.y, acc1.y);
        acc1.z = fmaf(x1, wv.z, acc1.z); acc1.w = fmaf(x1, wv.w, acc1.w);
        acc2.x = fmaf(x2, wv.x, acc2.x); acc2.y = fmaf(x2, wv.y, acc2.y);
        acc2.z = fmaf(x2, wv.z, acc2.z); acc2.w = fmaf(x2, wv.w, acc2.w);
        acc3.x = fmaf(x3, wv.x, acc3.x); acc3.y = fmaf(x3, wv.y, acc3.y);
        acc3.z = fmaf(x3, wv.z, acc3.z); acc3.w = fmaf(x3, wv.w, acc3.w);
    }

    const float4 avs = *(const float4*)(a2s + c0);
    const float4 avd = *(const float4*)(a2d + c0);
    float4 accs[4] = {acc0, acc1, acc2, acc3};
#pragma unroll
    for (int i = 0; i < 4; ++i) {
        int r = r_base + r0 + i;
        float4 a = accs[i];
        float ps = a.x * avs.x + a.y * avs.y + a.z * avs.z + a.w * avs.w;
        float pd = a.x * avd.x + a.y * avd.y + a.z * avd.z + a.w * avd.w;
        ps += __shfl_xor(ps, 1); pd += __shfl_xor(pd, 1);
        ps += __shfl_xor(ps, 2); pd += __shfl_xor(pd, 2);
        ps += __shfl_xor(ps, 4); pd += __shfl_xor(pd, 4);
        if (r < N) {
            *(float4*)(z2 + (size_t)r * 32 + c0) = a;
            if ((tid & 7) == 0) { as2[r] = ps; ad2[r] = pd; }
        }
    }
}

// ---------------- layer-2 aggregation + final linear (wave per dst node) ----------------
__global__ __launch_bounds__(256) void k_agg2(
    const int* __restrict__ rowp, const int* __restrict__ col,
    const float* __restrict__ as2, const float* __restrict__ ad2,
    const float* __restrict__ z2, const float* __restrict__ b2,
    const float* __restrict__ wl, const float* __restrict__ bl,
    float* __restrict__ out, int N)
{
    const int lane = threadIdx.x & 63;
    const int wid  = (blockIdx.x * 256 + threadIdx.x) >> 6;
    const int nw   = (gridDim.x * 256) >> 6;
    const int q  = lane >> 4;
    const int cl = lane & 15;
    for (int n = wid; n < N; n += nw) {
        const int start = rowp[n], end = rowp[n + 1];
        const float adn = ad2[n];
        float m = -1e30f, d = 0.f;
        for (int j = start + lane; j < end; j += 64) {
            int s = col[j];
            float e = leaky02(as2[s] + adn);
            float nm = fmaxf(m, e);
            d = d * __expf(m - nm) + __expf(e - nm);
            m = nm;
        }
#pragma unroll
        for (int sft = 1; sft < 64; sft <<= 1) {
            float om = __shfl_xor(m, sft), od = __shfl_xor(d, sft);
            float nm = fmaxf(m, om);
            d = d * __expf(m - nm) + od * __expf(om - nm);
            m = nm;
        }
        const float rd = 1.f / (d + 1e-16f);
        float2 acc = {0.f, 0.f};
        for (int j = start + q; j < end; j += 4) {
            int s = col[j];
            float alpha = __expf(leaky02(as2[s] + adn) - m) * rd;
            float2 zv = *(const float2*)(z2 + (size_t)s * 32 + cl * 2);
            acc.x = fmaf(alpha, zv.x, acc.x);
            acc.y = fmaf(alpha, zv.y, acc.y);
        }
        acc.x += __shfl_xor(acc.x, 16); acc.y += __shfl_xor(acc.y, 16);
        acc.x += __shfl_xor(acc.x, 32); acc.y += __shfl_xor(acc.y, 32);
        float h0 = eluf(acc.x + b2[cl * 2]);
        float h1v = eluf(acc.y + b2[cl * 2 + 1]);
        float p = h0 * wl[cl * 2] + h1v * wl[cl * 2 + 1];
#pragma unroll
        for (int sft = 1; sft < 16; sft <<= 1) p += __shfl_xor(p, sft);
        if (lane == 0) out[n] = p + bl[0];
    }
}

extern "C" void kernel_launch(void* const* d_in, const int* in_sizes, int n_in,
                              void* d_out, int out_size, void* d_ws, size_t ws_size,
                              hipStream_t stream) {
    const float* x   = (const float*)d_in[0];
    const int*   ei  = (const int*)d_in[1];
    const float* w1  = (const float*)d_in[2];
    const float* a1s = (const float*)d_in[3];
    const float* a1d = (const float*)d_in[4];
    const float* b1  = (const float*)d_in[5];
    const float* w2  = (const float*)d_in[6];
    const float* a2s = (const float*)d_in[7];
    const float* a2d = (const float*)d_in[8];
    const float* b2  = (const float*)d_in[9];
    const float* wl  = (const float*)d_in[10];
    const float* bl  = (const float*)d_in[11];
    float* out = (float*)d_out;

    const int N  = in_sizes[0] / 128;
    const int E  = in_sizes[1] / 2;
    const int Et = E + N;
    const int NB = (N + 1023) / 1024;

    float* ws   = (float*)d_ws;
    float* h1   = ws;                       // N*128
    float* out1 = h1   + (size_t)N * 128;   // N*128
    float* as1  = out1 + (size_t)N * 128;   // N*4
    float* ad1  = as1  + (size_t)N * 4;     // N*4
    float* z2   = ad1  + (size_t)N * 4;     // N*32
    float* as2  = z2   + (size_t)N * 32;    // N
    float* ad2  = as2  + N;                 // N
    int* counts = (int*)(ad2 + N);          // N
    int* rowp   = counts + N;               // N+1
    int* col    = rowp + (N + 1);           // Et
    int* pos    = col + Et;                 // N
    int* bsum   = pos + N;                  // NB
    int* boff   = bsum + NB;                // NB

    k_zero<<<(N + 255) / 256, 256, 0, stream>>>(counts, N);
    k_gemm1<<<2 * ((N + 63) / 64), 256, 0, stream>>>(x, w1, a1s, a1d, h1, as1, ad1, N);
    k_hist<<<(Et + 255) / 256, 256, 0, stream>>>(ei, counts, E, Et);
    k_bsum<<<NB, 256, 0, stream>>>(counts, bsum, N);
    k_scansums<<<1, 1024, 0, stream>>>(bsum, boff, rowp + N, NB);
    k_scatter<<<NB, 256, 0, stream>>>(counts, boff, rowp, pos, N);
    k_fill<<<(Et + 255) / 256, 256, 0, stream>>>(ei, pos, col, E, Et);
    k_agg1<<<4096, 256, 0, stream>>>(rowp, col, as1, ad1, h1, b1, out1, N);
    k_gemm2<<<(N + 127) / 128, 256, 0, stream>>>(out1, w2, a2s, a2d, z2, as2, ad2, N);
    k_agg2<<<4096, 256, 0, stream>>>(rowp, col, as2, ad2, z2, b2, wl, bl, out, N);
}